// Round 5
// baseline (666.609 us; speedup 1.0000x reference)
//
#include <hip/hip_runtime.h>

typedef _Float16 half8 __attribute__((ext_vector_type(8)));
typedef float floatx4 __attribute__((ext_vector_type(4)));

#define AS1 __attribute__((address_space(1)))
#define AS3 __attribute__((address_space(3)))

// s_waitcnt immediate: wait until <= n VMEM ops outstanding; expcnt/lgkmcnt = no-wait.
// gfx9/CDNA encoding: vmcnt[3:0]=imm[3:0], vmcnt[5:4]=imm[15:14], expcnt=imm[6:4], lgkm=imm[11:8]
#define WAIT_VMCNT(n) __builtin_amdgcn_s_waitcnt(((n) & 15) | (((n) >> 4) << 14) | (7 << 4) | (15 << 8))

// ---------------------------------------------------------------------------
// W transpose + fp32->fp16: W [1024][1024] (k,n) -> Wt [1024][1024] (n,k)
// ---------------------------------------------------------------------------
__global__ __launch_bounds__(256) void wtrans_kernel(
    const float* __restrict__ W0, const float* __restrict__ W1,
    const float* __restrict__ W2, _Float16* __restrict__ Wt)
{
    __shared__ _Float16 t[64 * 72];
    const float* W = (blockIdx.z == 0) ? W0 : (blockIdx.z == 1) ? W1 : W2;
    _Float16* O = Wt + (long)blockIdx.z * 1048576;
    const int tid = threadIdx.x;
    const int kb = blockIdx.y * 64, nb = blockIdx.x * 64;
#pragma unroll
    for (int i = 0; i < 4; i++) {
        int r = (tid >> 4) + i * 16;
        int c = (tid & 15) * 4;
        floatx4 w = *(const floatx4*)&W[(long)(kb + r) * 1024 + nb + c];
#pragma unroll
        for (int j = 0; j < 4; j++) t[(c + j) * 72 + r] = (_Float16)w[j];
    }
    __syncthreads();
    const int c = tid >> 2, rch = (tid & 3) * 16;
    half8 v0 = *(const half8*)&t[c * 72 + rch];
    half8 v1 = *(const half8*)&t[c * 72 + rch + 8];
    _Float16* o = &O[(long)(nb + c) * 1024 + kb + rch];
    *(half8*)o = v0;
    *(half8*)(o + 8) = v1;
}

// ---------------------------------------------------------------------------
// fp32 -> fp16 cast, 8 elems/thread, grid-stride
// ---------------------------------------------------------------------------
__global__ __launch_bounds__(256) void f32_to_f16_kernel(
    const float* __restrict__ in, _Float16* __restrict__ out, int n)
{
    for (long i = ((long)blockIdx.x * 256 + threadIdx.x) * 8; i < n;
         i += (long)gridDim.x * 256 * 8) {
        floatx4 a = *(const floatx4*)&in[i];
        floatx4 b = *(const floatx4*)&in[i + 4];
        half8 h;
#pragma unroll
        for (int e = 0; e < 4; e++) { h[e] = (_Float16)a[e]; h[e + 4] = (_Float16)b[e]; }
        *(half8*)&out[i] = h;
    }
}

// ---------------------------------------------------------------------------
// Producer-consumer GEMM: C[m][n] = sum_k A[m][k] * Bt[n][k] (fp16 row-major).
// 128x128 tile. 320 threads: waves 0-3 = consumers (4x4 16x16x32 MFMAs over a
// 64x64 quadrant each), wave 4 = producer (global->LDS DMA).
//
// K-loop has NO __syncthreads: producer streams 32-k slabs into a 3-slab LDS
// ring (48 KB), keeping 2 slabs of loads in flight (manual s_waitcnt
// vmcnt(32/16/0) bookkeeping); LDS-atomic ready/done counters synchronize.
// This removes the per-iteration vmcnt(0)+s_barrier drain that capped the
// 2-barrier structure at ~650-700 TF on these shapes.
//
// ready = # slabs whose DMA has completed (producer signals after vmcnt wait).
// done  = # (consumer wave, slab) completions; producer overwrites ring slot
//         (s+2)%3 only after done >= 4*s (all waves finished slab s-1).
//
// XCD swizzle: bid&7 = XCD, bid>>3 = slot (contiguous (z,y-slab) per XCD).
// LDS bank swizzle: col-group stored at slot p holds global group
// p ^ ((row>>1)&3); conflict-free b128 fragment reads (verified round 4:
// SQ_LDS_BANK_CONFLICT = 0).
//
// MODE 0: fp16 out row-major, (+bias per z)     (projQ/K fused)
// MODE 1: fp16 out TRANSPOSED per batch (+bias) (projV -> Vt [d][t])
// MODE 2: fp32 out row-major, * 1/R[row]        (PV -> d_out)
// MODE 3: fp16 out = exp(acc*scale), one 64-lane atomic row-sum add into R
// ---------------------------------------------------------------------------
template <int MODE>
__global__ __launch_bounds__(320) void gemm128_kernel(
    const _Float16* __restrict__ A, const _Float16* __restrict__ Bt,
    void* __restrict__ Cv, const float* __restrict__ bias,
    const float* __restrict__ bias2, float* __restrict__ R,
    int nx, int ny,
    int K, int lda, int ldb, int ldc,
    long aBatch, long bBatch, long cBatch, float scale)
{
    __shared__ _Float16 ring[3 * 8192];   // 3 slabs x (A 4096 | B 4096) halves
    __shared__ int ready;
    __shared__ int done;

    const int tid = threadIdx.x;
    if (tid == 0) { ready = 0; done = 0; }
    __syncthreads();

    // ---- XCD swizzle ----
    const int P = gridDim.x >> 3;
    const int g = (blockIdx.x & 7) * P + (blockIdx.x >> 3);
    const int pplane = nx * ny;
    const int z = g / pplane;
    const int rr = g - z * pplane;
    const int by = rr / nx;
    const int bx = rr - by * nx;
    const int m0 = by * 128, n0 = bx * 128;

    const _Float16* Ab = A + (long)z * aBatch;
    const _Float16* Bb = Bt + (long)z * bBatch;
    const int S = K >> 5;                 // number of 32-wide k slabs

    if (tid >= 256) {
        // ================= producer wave =================
        const int pl = tid - 256;                         // lane 0..63
        const int prow = pl >> 2;                         // 0..15
        const int pcol = (((pl & 3) ^ ((prow >> 1) & 3))) * 8;  // bank swizzle
        const _Float16* aB = Ab + (long)(m0 + prow) * lda + pcol;
        const _Float16* bB = Bb + (long)(n0 + prow) * ldb + pcol;

        auto issue = [&](int s) {
            _Float16* dst = ring + (s % 3) * 8192 + pl * 8;
            const _Float16* a = aB + s * 32;
            const _Float16* b = bB + s * 32;
#pragma unroll
            for (int i = 0; i < 8; i++)
                __builtin_amdgcn_global_load_lds(
                    (AS1 void*)(a + (long)i * 16 * lda), (AS3 void*)(dst + i * 512), 16, 0, 0);
#pragma unroll
            for (int i = 0; i < 8; i++)
                __builtin_amdgcn_global_load_lds(
                    (AS1 void*)(b + (long)i * 16 * ldb), (AS3 void*)(dst + 4096 + i * 512), 16, 0, 0);
        };

        issue(0);
        issue(1);
        int dn = 0;
        for (int s = 0; s + 2 < S; s++) {
            if (s >= 1 && dn < 4 * s) {
                do {
                    dn = __hip_atomic_load(&done, __ATOMIC_ACQUIRE, __HIP_MEMORY_SCOPE_WORKGROUP);
                    if (dn < 4 * s) __builtin_amdgcn_s_sleep(1);
                } while (dn < 4 * s);
            }
            issue(s + 2);                     // ring slot (s+2)%3, freed above
            WAIT_VMCNT(32);                   // slab s complete (s+1,s+2 in flight)
            __hip_atomic_store(&ready, s + 1, __ATOMIC_RELEASE, __HIP_MEMORY_SCOPE_WORKGROUP);
        }
        WAIT_VMCNT(16);                       // slab S-2 complete
        __hip_atomic_store(&ready, S - 1, __ATOMIC_RELEASE, __HIP_MEMORY_SCOPE_WORKGROUP);
        WAIT_VMCNT(0);                        // slab S-1 complete
        __hip_atomic_store(&ready, S, __ATOMIC_RELEASE, __HIP_MEMORY_SCOPE_WORKGROUP);
        if constexpr (MODE == 1) { __syncthreads(); __syncthreads(); }  // match epilogue barriers
        return;
    }

    // ================= consumer waves =================
    const int wave = tid >> 6, lane = tid & 63;
    const int quad = lane >> 4, lr = lane & 15;
    const int wm = wave & 1, wn = wave >> 1;
    const int slotA = (quad ^ ((lr >> 1) & 3)) * 8;

    floatx4 acc[4][4] = {};
    int rdy = 0;

    for (int s = 0; s < S; s++) {
        if (rdy < s + 1) {
            do {
                rdy = __hip_atomic_load(&ready, __ATOMIC_ACQUIRE, __HIP_MEMORY_SCOPE_WORKGROUP);
            } while (rdy < s + 1);
        }
        const _Float16* As = ring + (s % 3) * 8192;
        const _Float16* Bs = As + 4096;
        half8 aF[4], bF[4];
#pragma unroll
        for (int i = 0; i < 4; i++) {
            aF[i] = *(const half8*)&As[(wm * 64 + i * 16 + lr) * 32 + slotA];
            bF[i] = *(const half8*)&Bs[(wn * 64 + i * 16 + lr) * 32 + slotA];
        }
#pragma unroll
        for (int mi = 0; mi < 4; mi++)
#pragma unroll
            for (int ni = 0; ni < 4; ni++)
                acc[mi][ni] = __builtin_amdgcn_mfma_f32_16x16x32_f16(
                    aF[mi], bF[ni], acc[mi][ni], 0, 0, 0);
        if (lane == 0)
            __hip_atomic_fetch_add(&done, 1, __ATOMIC_RELEASE, __HIP_MEMORY_SCOPE_WORKGROUP);
    }

    // ---- epilogue ----  C/D frag: m = quad*4+reg, n = lane&15
    if constexpr (MODE == 0) {
        _Float16* C = (_Float16*)Cv + (long)z * cBatch;
        const float* bz = (z == 0 || !bias2) ? bias : bias2;
#pragma unroll
        for (int ni = 0; ni < 4; ni++) {
            const int n = n0 + wn * 64 + ni * 16 + lr;
            const float bv_ = bz ? bz[n] : 0.0f;
#pragma unroll
            for (int mi = 0; mi < 4; mi++) {
                const int mb = m0 + wm * 64 + mi * 16 + quad * 4;
#pragma unroll
                for (int r = 0; r < 4; r++)
                    C[(long)(mb + r) * ldc + n] = (_Float16)(acc[mi][ni][r] + bv_);
            }
        }
    } else if constexpr (MODE == 1) {
        __syncthreads();               // all consumer slab reads done (ring dies)
        _Float16* ctile = ring;        // 128 x 136 fp16 = 34 KB, fits the ring
#pragma unroll
        for (int ni = 0; ni < 4; ni++) {
            const int nl = wn * 64 + ni * 16 + lr;
            const float bv_ = bias ? bias[n0 + nl] : 0.0f;
#pragma unroll
            for (int mi = 0; mi < 4; mi++) {
                const int ml = wm * 64 + mi * 16 + quad * 4;
#pragma unroll
                for (int r = 0; r < 4; r++)
                    ctile[nl * 136 + ml + r] = (_Float16)(acc[mi][ni][r] + bv_);
            }
        }
        __syncthreads();
        _Float16* C = (_Float16*)Cv + (long)(m0 >> 11) * cBatch;  // batch from m
        const int t0 = m0 & 2047;
#pragma unroll
        for (int p = 0; p < 8; p++) {
            const int row = p * 16 + (tid >> 4);
            const int seg = (tid & 15) * 8;
            half8 v = *(const half8*)&ctile[row * 136 + seg];
            *(half8*)&C[(long)(n0 + row) * ldc + t0 + seg] = v;
        }
    } else if constexpr (MODE == 2) {
        float* C = (float*)Cv + (long)z * cBatch;
        const float* Rz = R + (long)z * 2048;
        float inv[4][4];
#pragma unroll
        for (int mi = 0; mi < 4; mi++) {
            const int mb = m0 + wm * 64 + mi * 16 + quad * 4;
#pragma unroll
            for (int r = 0; r < 4; r++) inv[mi][r] = 1.0f / Rz[mb + r];
        }
#pragma unroll
        for (int ni = 0; ni < 4; ni++) {
            const int n = n0 + wn * 64 + ni * 16 + lr;
#pragma unroll
            for (int mi = 0; mi < 4; mi++) {
                const int mb = m0 + wm * 64 + mi * 16 + quad * 4;
#pragma unroll
                for (int r = 0; r < 4; r++)
                    C[(long)(mb + r) * ldc + n] = acc[mi][ni][r] * inv[mi][r];
            }
        }
    } else {  // MODE 3: scores -> E = exp(acc*scale), row sums into R
        _Float16* C = (_Float16*)Cv + (long)z * cBatch;
        float* Rz = R + (long)z * 2048;
        float rs[4][4] = {};
#pragma unroll
        for (int ni = 0; ni < 4; ni++) {
            const int n = n0 + wn * 64 + ni * 16 + lr;
#pragma unroll
            for (int mi = 0; mi < 4; mi++) {
                const int mb = m0 + wm * 64 + mi * 16 + quad * 4;
#pragma unroll
                for (int r = 0; r < 4; r++) {
                    float e = __expf(acc[mi][ni][r] * scale);
                    C[(long)(mb + r) * ldc + n] = (_Float16)e;
                    rs[mi][r] += e;
                }
            }
        }
        // butterfly over the 16 lr-lanes of each quad -> rs uniform per quad
#pragma unroll
        for (int off = 1; off < 16; off <<= 1)
#pragma unroll
            for (int mi = 0; mi < 4; mi++)
#pragma unroll
                for (int r = 0; r < 4; r++)
                    rs[mi][r] += __shfl_xor(rs[mi][r], off, 64);
        // one atomic per LANE (64 distinct rows per wave) instead of 16 serial
        float myv = rs[0][0];
#pragma unroll
        for (int mi = 0; mi < 4; mi++)
#pragma unroll
            for (int r = 0; r < 4; r++)
                if (lr == mi * 4 + r) myv = rs[mi][r];
        atomicAdd(&Rz[m0 + wm * 64 + (lr >> 2) * 16 + quad * 4 + (lr & 3)], myv);
    }
}

// ---------------------------------------------------------------------------
// B=8, S=2048, D=1024.  Workspace layout (bytes):
//   Q   fp16 [16384][1024]            @ 0          (33,554,432)
//   Kb  fp16 [16384][1024]            @ 33,554,432 (33,554,432)
//   Vt  fp16 [8][1024][2048]          @ 67,108,864 (33,554,432)
//   Sc  fp16 [8][2048][2048]          @ 100,663,296 (67,108,864)  (xb aliased)
//   Wt  fp16 [3][1024][1024]          @ 167,772,160 (6,291,456)
//   R   fp32 [8][2048]                @ 174,063,616 (65,536)
// total 174,129,152
// ---------------------------------------------------------------------------
extern "C" void kernel_launch(void* const* d_in, const int* in_sizes, int n_in,
                              void* d_out, int out_size, void* d_ws, size_t ws_size,
                              hipStream_t stream)
{
    const float* x  = (const float*)d_in[0];
    const float* Wq = (const float*)d_in[1];
    const float* bq = (const float*)d_in[2];
    const float* Wk = (const float*)d_in[3];
    const float* bk = (const float*)d_in[4];
    const float* Wv = (const float*)d_in[5];
    const float* bv = (const float*)d_in[6];

    if (ws_size < 174129152u) return;  // cannot run

    char* ws = (char*)d_ws;
    _Float16* Q  = (_Float16*)(ws + 0);
    _Float16* Vt = (_Float16*)(ws + 67108864);
    _Float16* Sc = (_Float16*)(ws + 100663296);
    _Float16* Wt = (_Float16*)(ws + 167772160);
    float*    R  = (float*)(ws + 174063616);
    _Float16* xb = Sc;  // aliased: xb dead before Sc is written
    _Float16* Kb = Q + 16777216;
    float* out = (float*)d_out;

    hipMemsetAsync(R, 0, 65536, stream);
    wtrans_kernel<<<dim3(16, 16, 3), 256, 0, stream>>>(Wq, Wk, Wv, Wt);
    f32_to_f16_kernel<<<2048, 256, 0, stream>>>(x, xb, 16777216);

    // Q and K projections fused via z: M=16384, N=1024, K=1024, 2048 blocks
    gemm128_kernel<0><<<2048, 320, 0, stream>>>(
        xb, Wt, Q, bq, bk, nullptr, 8, 128, 1024, 1024, 1024, 1024,
        0, 1048576, 16777216, 1.0f);
    // V projection -> Vt [b][d][t], 1024 blocks
    gemm128_kernel<1><<<1024, 320, 0, stream>>>(
        xb, Wt + 2097152, Vt, bv, nullptr, nullptr, 8, 128, 1024, 1024, 1024, 2048,
        0, 0, 2097152, 1.0f);

    // scores: E = exp(QK^T/32), row sums -> R. per-batch M=N=2048, K=1024
    gemm128_kernel<3><<<2048, 320, 0, stream>>>(
        Q, Kb, Sc, nullptr, nullptr, R, 16, 16, 1024, 1024, 1024, 2048,
        2097152, 2097152, 4194304, 0.03125f);

    // out = (E V) / R : per-batch M=2048, N=1024, K=2048
    gemm128_kernel<2><<<1024, 320, 0, stream>>>(
        Sc, Vt, out, nullptr, nullptr, R, 8, 16, 2048, 2048, 2048, 1024,
        4194304, 2097152, 2097152, 1.0f);
}